// Round 3
// baseline (508.897 us; speedup 1.0000x reference)
//
#include <hip/hip_runtime.h>

typedef unsigned short u16;
typedef __attribute__((ext_vector_type(8))) short bf16x8;
typedef __attribute__((ext_vector_type(4))) float f32x4;

// Problem constants
#define LSEQ 512
#define BN   64
#define DD   128
#define HH   128
#define CHUNK 64    // embed rows staged in LDS per refill (16 KiB bf16)

// fp32 inputs (verified R7 diagnostic); one fp32 scalar output (R8-R11 PASS).

__device__ __forceinline__ u16 f2b(float f) {
  union { float f; unsigned i; } v; v.f = f;
  unsigned i = v.i;
  return (u16)((i + 0x7fffu + ((i >> 16) & 1u)) >> 16);
}
__device__ __forceinline__ float rcpf(float x) {
  return __builtin_amdgcn_rcpf(x);
}
__device__ __forceinline__ float sigm(float x) {
  return rcpf(1.f + __expf(-x));               // v_exp + v_rcp, no div chain
}
__device__ __forceinline__ float tanh_f(float x) {
  x = fminf(15.f, fmaxf(-15.f, x));
  float e = __expf(2.f * x);
  return (e - 1.f) * rcpf(e + 1.f);
}
__device__ __forceinline__ float clampg(float x, float hi) {
  return fmaxf(-hi, fminf(hi, x));  // transparent: true |gates|<0.5
}

// ---------------------------------------------------------------------------
// Two 512-step recurrences, fused. blockIdx 0..63: fwd LSTM sample b;
// 64..127: tree-LSTM chain (left-deep). Block = 256 threads (4 WAVES).
//
// Round-15 (this round): 4-wave restructure (was 8).
//  * R2's null result (removing DS ops changed nothing) + R0->R1's -500cyc
//    (removing in-order MFMA+read work) => the step is bound by the
//    phase-locked per-step pipeline: 40 redundant aK b128-reads/CU, 8-wave
//    barrier spread, in-order issue. Halving waves halves the redundant
//    LDS traffic (24 reads/CU/step) and barrier width; MFMA and VALU work
//    per SIMD are unchanged (each wave now owns 32 dims = 8 col-tiles,
//    2 gate-quadruples per lane).
//  * Both H- and E-weight fragments resident: 64 frags = 256 VGPR + acc;
//    ~390 VGPR total, legal for 256-thr block (1 wave/SIMD), under the
//    450-reg spill threshold.
//  * estage lane stride padded to 48 B (2-way max bank conflict on reads).
//  * Bit-exact vs R14: same MFMA tile arithmetic per element, same ks chain
//    order, same (acch + ev) + bias order, same f2b rounding.
//  * Zero global memory ops inside the step loop (echunk staging, R11).
// ---------------------------------------------------------------------------
__global__ __launch_bounds__(256, 1) void chains_kernel(
    const int* __restrict__ x, const int* __restrict__ lengths,
    const float* __restrict__ embed,
    const float* __restrict__ Wih_f, const float* __restrict__ Whh_f,
    const float* __restrict__ b_f,
    const float* __restrict__ Wiou, const float* __restrict__ Uiou,
    const float* __restrict__ biou,
    const float* __restrict__ Wf, const float* __restrict__ Uf,
    const float* __restrict__ bfv,
    float* __restrict__ sent_vec, float* __restrict__ t_state,
    float* __restrict__ t_hidden) {
  const bool tree = blockIdx.x >= BN;
  const int b = blockIdx.x & (BN - 1);
  int len = lengths[b];
  len = (len < 1) ? 1 : (len > LSEQ ? LSEQ : len);
  const int tid = threadIdx.x;
  const int w = tid >> 6, l = tid & 63, lr = l & 15, lq = l >> 4;
  const int d0 = w * 32 + lr;   // lane's hh=0 dim
  // hh=1 dim is d0+16.

  __shared__ __align__(16) u16 echunk[CHUNK * 128];        // e rows, bf16, swizzled
  __shared__ __align__(16) float estage[4 * 16 * 16 * 12]; // [w][s][lr][12]: 8 used
  __shared__ __align__(16) u16 aK[2][128];                 // h bf16, double-buffered
  __shared__ int toks[LSEQ];                               // token ids (clamped)

  // ---- Resident B fragments: [gate g][half hh][ks]. Tile (g,hh) of wave w
  // covers gate columns n = gbase(g) + w*32 + hh*16 + lr. MFMA #ks consumes
  // B[k = ks*32 + lq*8 + j][n], j = 0..7.
  bf16x8 bfragH[4][2][4], bfragE[4][2][4];
  if (!tree) {
#pragma unroll
    for (int g = 0; g < 4; g++)
#pragma unroll
      for (int hh = 0; hh < 2; hh++) {
        const int n = g * 128 + w * 32 + hh * 16 + lr;
#pragma unroll
        for (int ks = 0; ks < 4; ks++) {
          const int k0 = ks * 32 + lq * 8;
          {
            float4 lo = *(const float4*)(Whh_f + n * 128 + k0);
            float4 hi = *(const float4*)(Whh_f + n * 128 + k0 + 4);
            bf16x8 fr;
            fr[0] = (short)f2b(lo.x); fr[1] = (short)f2b(lo.y);
            fr[2] = (short)f2b(lo.z); fr[3] = (short)f2b(lo.w);
            fr[4] = (short)f2b(hi.x); fr[5] = (short)f2b(hi.y);
            fr[6] = (short)f2b(hi.z); fr[7] = (short)f2b(hi.w);
            bfragH[g][hh][ks] = fr;
          }
          {
            float4 lo = *(const float4*)(Wih_f + n * 128 + k0);
            float4 hi = *(const float4*)(Wih_f + n * 128 + k0 + 4);
            bf16x8 fr;
            fr[0] = (short)f2b(lo.x); fr[1] = (short)f2b(lo.y);
            fr[2] = (short)f2b(lo.z); fr[3] = (short)f2b(lo.w);
            fr[4] = (short)f2b(hi.x); fr[5] = (short)f2b(hi.y);
            fr[6] = (short)f2b(hi.z); fr[7] = (short)f2b(hi.w);
            bfragE[g][hh][ks] = fr;
          }
        }
      }
  } else {
#pragma unroll
    for (int g = 0; g < 4; g++)
#pragma unroll
      for (int hh = 0; hh < 2; hh++) {
        const int dcol = w * 32 + hh * 16 + lr;
#pragma unroll
        for (int ks = 0; ks < 4; ks++) {
          const int k0 = ks * 32 + lq * 8;
          bf16x8 fh, fe;
#pragma unroll
          for (int j = 0; j < 8; j++) {
            const int k = k0 + j;
            float vh, ve;
            if (g < 3) { vh = Uiou[k * 384 + g * 128 + dcol];
                         ve = Wiou[k * 384 + g * 128 + dcol]; }
            else       { vh = Uf[k * 128 + dcol];
                         ve = Wf[k * 128 + dcol]; }
            fh[j] = (short)f2b(vh);
            fe[j] = (short)f2b(ve);
          }
          bfragH[g][hh][ks] = fh;
          bfragE[g][hh][ks] = fe;
        }
      }
  }

  // Per-lane biases for the 4 gates of d0 (A-suffix) and d0+16 (B-suffix).
  float bA0, bA1, bA2, bA3, bB0, bB1, bB2, bB3;
  if (!tree) {
    bA0 = b_f[d0];        bA1 = b_f[128 + d0];
    bA2 = b_f[256 + d0];  bA3 = b_f[384 + d0];
    bB0 = b_f[d0 + 16];       bB1 = b_f[128 + d0 + 16];
    bB2 = b_f[256 + d0 + 16]; bB3 = b_f[384 + d0 + 16];
  } else {
    bA0 = biou[d0];       bA1 = biou[128 + d0];
    bA2 = biou[256 + d0]; bA3 = bfv[d0];
    bB0 = biou[d0 + 16];       bB1 = biou[128 + d0 + 16];
    bB2 = biou[256 + d0 + 16]; bB3 = bfv[d0 + 16];
  }

  // Token ids -> LDS (clamped); h(0) = 0 in both buffers.
  for (int i = tid; i < LSEQ; i += 256) {
    int tt = (i < len) ? i : (len - 1);
    toks[i] = x[tt * BN + b];
  }
  if (tid < HH) { aK[0][tid] = 0; aK[1][tid] = 0; }

  // Per-lane LDS byte bases (loop-invariant; per-step offsets are immediates).
  // estage cell (w,s,lr) = 48 B: [hh0: g0..g3][hh1: g0..g3][16B pad].
  char* const es_base = (char*)estage;
  const int erd = w * 12288 + lr * 48;                   // + S*768 (+16 for hh1)
  const int ewr = w * 12288 + lq * 3072 + lr * 48;       // + rg*768
  const char* const ak_rd = (const char*)aK + (lq << 4); // + (S&1)*256 + ks*64
  u16* const ak_wr = &aK[0][w * 32 + (l & 31)];          // + ((S&1)^1)*128

  const f32x4 zf = (f32x4){0.f, 0.f, 0.f, 0.f};
  float c0 = 0.f, h0 = 0.f, c1 = 0.f, h1 = 0.f;
  int t = 0;

// ---- Batched e-half for steps [T0, T0+16): A row r = e(T0+r), r = lane&15.
// C-layout: lane lq*16+lr, reg rg holds step lq*4+rg for col lr.
#define EBATCH(T0)                                                            \
  {                                                                           \
    const int rb = ((T0) & (CHUNK - 1)) + lr;                                 \
    bf16x8 ae[4];                                                             \
    _Pragma("unroll")                                                         \
    for (int ks = 0; ks < 4; ks++) {                                          \
      int bo = (rb * 256 + ks * 64 + lq * 16) ^ ((rb & 7) << 4);              \
      ae[ks] = *(const bf16x8*)((const char*)echunk + bo);                    \
    }                                                                         \
    f32x4 EBv[4][2];                                                          \
    _Pragma("unroll")                                                         \
    for (int g = 0; g < 4; g++)                                               \
      _Pragma("unroll")                                                       \
      for (int hh = 0; hh < 2; hh++)                                          \
        EBv[g][hh] = __builtin_amdgcn_mfma_f32_16x16x32_bf16(                 \
            ae[0], bfragE[g][hh][0], zf, 0, 0, 0);                            \
    _Pragma("unroll")                                                         \
    for (int ks = 1; ks < 4; ks++)                                            \
      _Pragma("unroll")                                                       \
      for (int g = 0; g < 4; g++)                                             \
        _Pragma("unroll")                                                     \
        for (int hh = 0; hh < 2; hh++)                                        \
          EBv[g][hh] = __builtin_amdgcn_mfma_f32_16x16x32_bf16(               \
              ae[ks], bfragE[g][hh][ks], EBv[g][hh], 0, 0, 0);                \
    _Pragma("unroll")                                                         \
    for (int rg = 0; rg < 4; rg++) {                                          \
      f32x4 w0 = {EBv[0][0][rg], EBv[1][0][rg], EBv[2][0][rg], EBv[3][0][rg]};\
      f32x4 w1 = {EBv[0][1][rg], EBv[1][1][rg], EBv[2][1][rg], EBv[3][1][rg]};\
      *(f32x4*)(es_base + ewr + rg * 768) = w0;                               \
      *(f32x4*)(es_base + ewr + rg * 768 + 16) = w1;                          \
    }                                                                         \
  }

// ---- One step, compile-time step index S in [0,16).
#define STEPB(S)                                                              \
  {                                                                           \
    bf16x8 ah[4];                                                             \
    _Pragma("unroll")                                                         \
    for (int ks = 0; ks < 4; ks++)                                            \
      ah[ks] = *(const bf16x8*)(ak_rd + ((S) & 1) * 256 + ks * 64);           \
    f32x4 ev0 = *(const f32x4*)(es_base + erd + (S) * 768);                   \
    f32x4 ev1 = *(const f32x4*)(es_base + erd + (S) * 768 + 16);              \
    f32x4 acch[4][2];                                                         \
    _Pragma("unroll")                                                         \
    for (int g = 0; g < 4; g++)                                               \
      _Pragma("unroll")                                                       \
      for (int hh = 0; hh < 2; hh++)                                          \
        acch[g][hh] = __builtin_amdgcn_mfma_f32_16x16x32_bf16(                \
            ah[0], bfragH[g][hh][0], zf, 0, 0, 0);                            \
    _Pragma("unroll")                                                         \
    for (int ks = 1; ks < 4; ks++)                                            \
      _Pragma("unroll")                                                       \
      for (int g = 0; g < 4; g++)                                             \
        _Pragma("unroll")                                                     \
        for (int hh = 0; hh < 2; hh++)                                        \
          acch[g][hh] = __builtin_amdgcn_mfma_f32_16x16x32_bf16(              \
              ah[ks], bfragH[g][hh][ks], acch[g][hh], 0, 0, 0);               \
    float gA0 = clampg(acch[0][0][0] + ev0[0] + bA0, 16.f);                   \
    float gA1 = clampg(acch[1][0][0] + ev0[1] + bA1, 16.f);                   \
    float gA2 = clampg(acch[2][0][0] + ev0[2] + bA2, 16.f);                   \
    float gA3 = clampg(acch[3][0][0] + ev0[3] + bA3, 16.f);                   \
    float gB0 = clampg(acch[0][1][0] + ev1[0] + bB0, 16.f);                   \
    float gB1 = clampg(acch[1][1][0] + ev1[1] + bB1, 16.f);                   \
    float gB2 = clampg(acch[2][1][0] + ev1[2] + bB2, 16.f);                   \
    float gB3 = clampg(acch[3][1][0] + ev1[3] + bB3, 16.f);                   \
    if (!tree) {                                                              \
      float iA = sigm(gA0), fA = sigm(gA1), gA = tanh_f(gA2), oA = sigm(gA3); \
      c0 = fA * c0 + iA * gA;  h0 = oA * tanh_f(c0);                          \
      float iB = sigm(gB0), fB = sigm(gB1), gB = tanh_f(gB2), oB = sigm(gB3); \
      c1 = fB * c1 + iB * gB;  h1 = oB * tanh_f(c1);                          \
    } else {                                                                  \
      float iA = sigm(gA0), oA = sigm(gA1), uA = tanh_f(gA2), fA = sigm(gA3); \
      c0 = iA * uA + fA * c0;  h0 = oA * tanh_f(c0);                          \
      float iB = sigm(gB0), oB = sigm(gB1), uB = tanh_f(gB2), fB = sigm(gB3); \
      c1 = iB * uB + fB * c1;  h1 = oB * tanh_f(c1);                          \
    }                                                                         \
    float hsel = (l < 16) ? h0 : h1;                                          \
    if (l < 32) ak_wr[(((S) & 1) ^ 1) * 128] = f2b(hsel);                     \
    __syncthreads();                                                          \
  }

// Tail step: block-uniform predicate (tend identical across waves).
#define STEPT(S) if (tb + (S) < tend) STEPB(S)

  for (int c0i = 0; c0i < len; c0i += CHUNK) {
    __syncthreads();  // prev chunk fully consumed (and toks/h0 visible)

    // ---- Refill: stage rows [c0i, c0i+CHUNK) as bf16 into echunk (swizzled).
#pragma unroll
    for (int j = 0; j < 8; j++) {
      int u = tid + j * 256;
      int r = u >> 5;
      int c4 = (u & 31) * 4;
      int row = toks[c0i + r];
      float4 v = *(const float4*)(embed + (size_t)row * DD + c4);
      u16 eb[4] = {f2b(v.x), f2b(v.y), f2b(v.z), f2b(v.w)};
      int bo = (r * 256 + c4 * 2) ^ ((r & 7) << 4);
      *(unsigned long long*)((char*)echunk + bo) =
          *(const unsigned long long*)eb;
    }
    __syncthreads();  // chunk visible

    const int tend = (c0i + CHUNK < len) ? c0i + CHUNK : len;
    // Full 16-step groups: no per-step checks, all offsets immediate.
    while (t + 16 <= tend) {
      EBATCH(t)
      STEPB(0)  STEPB(1)  STEPB(2)  STEPB(3)
      STEPB(4)  STEPB(5)  STEPB(6)  STEPB(7)
      STEPB(8)  STEPB(9)  STEPB(10) STEPB(11)
      STEPB(12) STEPB(13) STEPB(14) STEPB(15)
      t += 16;
    }
    // Tail group (only at the very end of the sequence).
    if (t < tend) {
      const int tb = t;
      EBATCH(tb)
      STEPT(0)  STEPT(1)  STEPT(2)  STEPT(3)
      STEPT(4)  STEPT(5)  STEPT(6)  STEPT(7)
      STEPT(8)  STEPT(9)  STEPT(10) STEPT(11)
      STEPT(12) STEPT(13) STEPT(14)
      t = tend;
    }
  }
#undef STEPT
#undef STEPB
#undef EBATCH

  if (l < 32) {
    const int dd = w * 32 + l;
    if (!tree) {
      sent_vec[b * HH + dd] = (l < 16) ? h0 : h1;
    } else {
      t_state[b * HH + dd] = (l < 16) ? c0 : c1;
      t_hidden[b * HH + dd] = (l < 16) ? h0 : h1;
    }
  }
}

// ---------------------------------------------------------------------------
// Head: tree_out = [t_state | w1*t_hidden + w2*sent_vec]; sigmoid logits ->
// clipped BCE vs one-hot(y); loss = -mean over (B, NC=2) = 128 terms. fp32.
// ---------------------------------------------------------------------------
__global__ __launch_bounds__(128) void final_kernel(
    const int* __restrict__ y, const float* __restrict__ sent_vec,
    const float* __restrict__ t_state, const float* __restrict__ t_hidden,
    const float* __restrict__ Wout, const float* __restrict__ bout,
    const float* __restrict__ w1, const float* __restrict__ w2,
    float* __restrict__ out) {
  int tid = threadIdx.x;  // (b, cls)
  int b = tid >> 1, cls = tid & 1;
  float W1 = w1[0], W2 = w2[0];
  const float* wrow = Wout + cls * 256;
  float acc = bout[cls];
  for (int j = 0; j < HH; j++)
    acc += t_state[b * HH + j] * wrow[j];
  for (int j = 0; j < HH; j++)
    acc += (W1 * t_hidden[b * HH + j] + W2 * sent_vec[b * HH + j]) * wrow[128 + j];
  float p = 1.f / (1.f + __expf(-acc));
  p = fminf(1.f - 1e-7f, fmaxf(1e-7f, p));
  int yy = y[b]; yy = yy < 0 ? 0 : (yy > 1 ? 1 : yy);
  float term = (cls == yy) ? __logf(p) : __logf(1.f - p);
  __shared__ float red[128];
  red[tid] = term;
  __syncthreads();
  for (int s = 64; s > 0; s >>= 1) {
    if (tid < s) red[tid] += red[tid + s];
    __syncthreads();
  }
  if (tid == 0) out[0] = -red[0] / 128.f;
}

// ---------------------------------------------------------------------------
extern "C" void kernel_launch(void* const* d_in, const int* in_sizes, int n_in,
                              void* d_out, int out_size, void* d_ws, size_t ws_size,
                              hipStream_t stream) {
  (void)in_sizes; (void)n_in; (void)out_size; (void)ws_size;
  const int*   x       = (const int*)d_in[0];
  const int*   y       = (const int*)d_in[1];
  // d_in[2] = p (unused by reference)
  const int*   lengths = (const int*)d_in[3];
  // d_in[4], d_in[5] = left/right child: fixed left-deep chain (j-1 / -1)
  const float* embed   = (const float*)d_in[6];
  const float* Wih_f   = (const float*)d_in[7];
  const float* Whh_f   = (const float*)d_in[8];
  const float* b_f     = (const float*)d_in[9];
  // d_in[10..12] = backward-LSTM weights (result unused by reference)
  const float* Wiou    = (const float*)d_in[13];
  const float* Uiou    = (const float*)d_in[14];
  const float* biou    = (const float*)d_in[15];
  const float* Wf      = (const float*)d_in[16];
  const float* Uf      = (const float*)d_in[17];
  const float* bfv     = (const float*)d_in[18];
  const float* Wout    = (const float*)d_in[19];
  const float* bout    = (const float*)d_in[20];
  const float* w1      = (const float*)d_in[21];
  const float* w2      = (const float*)d_in[22];

  // Workspace: 3 fp32 [64][128] vectors = 96 KiB.
  float* sent_vec = (float*)d_ws;
  float* t_state  = sent_vec + BN * HH;
  float* t_hidden = t_state + BN * HH;

  chains_kernel<<<128, 256, 0, stream>>>(x, lengths, embed,
                                         Wih_f, Whh_f, b_f,
                                         Wiou, Uiou, biou, Wf, Uf, bfv,
                                         sent_vec, t_state, t_hidden);
  final_kernel<<<1, 128, 0, stream>>>(y, sent_vec, t_state, t_hidden,
                                      Wout, bout, w1, w2, (float*)d_out);
}

// Round 4
// 378.425 us; speedup vs baseline: 1.3448x; 1.3448x over previous
//
#include <hip/hip_runtime.h>

typedef unsigned short u16;
typedef __attribute__((ext_vector_type(8))) short bf16x8;
typedef __attribute__((ext_vector_type(4))) float f32x4;

// Problem constants
#define LSEQ 512
#define BN   64
#define DD   128
#define HH   128
#define CHUNK 64    // embed rows staged in LDS per refill (16 KiB bf16)

// fp32 inputs (verified R7 diagnostic); one fp32 scalar output (R8-R11 PASS).

__device__ __forceinline__ u16 f2b(float f) {
  union { float f; unsigned i; } v; v.f = f;
  unsigned i = v.i;
  return (u16)((i + 0x7fffu + ((i >> 16) & 1u)) >> 16);
}
__device__ __forceinline__ unsigned cvt_pk_bf16(float lo, float hi) {
  unsigned r;
  asm("v_cvt_pk_bf16_f32 %0, %1, %2" : "=v"(r) : "v"(lo), "v"(hi));
  return r;  // [15:0]=bf16(lo), [31:16]=bf16(hi), RNE (same bits as f2b)
}
__device__ __forceinline__ float rcpf(float x) {
  return __builtin_amdgcn_rcpf(x);
}
__device__ __forceinline__ float sigm(float x) {
  return rcpf(1.f + __expf(-x));               // v_exp + v_rcp, no div chain
}
__device__ __forceinline__ float tanh_f(float x) {
  x = fminf(15.f, fmaxf(-15.f, x));
  float e = __expf(2.f * x);
  return (e - 1.f) * rcpf(e + 1.f);
}

// ---------------------------------------------------------------------------
// Two 512-step recurrences, fused. blockIdx 0..63: fwd LSTM sample b;
// 64..127: tree-LSTM chain (left-deep). Block = 512 threads (8 waves) — the
// R2 structure (register cap: ~256 v+a per wave at 2 waves/SIMD; R3's
// 4-wave/double-tile variant spilled and regressed 270->393us).
//
// Round-16 (this round): serial-chain surgery, register-conscious.
//  * Pair-split MFMA chain: depth 4 -> 2 (accA=ks1(ks0), accB=ks3(ks2),
//    gate=(accA[0]+accB[0])+ev). +16 regs (fits ~30-reg headroom), saves
//    ~2 MFMA latencies per step off the critical path.
//  * Gate biases baked into estage at EBATCH-write (off-path, amortized
//    1/16 steps) -> one serial add removed per gate.
//  * clampg dropped (measured transparent: true |gates| < 0.5).
//  * h bf16 conversion via single v_cvt_pk_bf16_f32 (was 3-op f2b).
//  * Step latency model: barrier -> ds_read(~120cy) -> MFMA chain -> VALU
//    nonlin -> cvt -> ds_write -> barrier. R1/R2 nulls showed DS-issue and
//    instruction count are NOT the bound; only chain links count.
//  * Zero global memory ops inside the step loop (echunk staging, R11).
// ---------------------------------------------------------------------------
__global__ __launch_bounds__(512, 1) void chains_kernel(
    const int* __restrict__ x, const int* __restrict__ lengths,
    const float* __restrict__ embed,
    const float* __restrict__ Wih_f, const float* __restrict__ Whh_f,
    const float* __restrict__ b_f,
    const float* __restrict__ Wiou, const float* __restrict__ Uiou,
    const float* __restrict__ biou,
    const float* __restrict__ Wf, const float* __restrict__ Uf,
    const float* __restrict__ bfv,
    float* __restrict__ sent_vec, float* __restrict__ t_state,
    float* __restrict__ t_hidden) {
  const bool tree = blockIdx.x >= BN;
  const int b = blockIdx.x & (BN - 1);
  int len = lengths[b];
  len = (len < 1) ? 1 : (len > LSEQ ? LSEQ : len);
  const int tid = threadIdx.x;
  const int w = tid >> 6, l = tid & 63, lr = l & 15, lq = l >> 4;
  const int d = w * 16 + lr;  // hidden index this lane's gates belong to

  __shared__ __align__(16) u16 echunk[CHUNK * 128];  // staged e rows, bf16 (XOR-swizzled)
  __shared__ __align__(16) float estage[8 * 16 * 16 * 4];  // [w][s][lr][g] fp32 (bias baked)
  __shared__ __align__(16) u16 aK[2][128];           // h bf16, double-buffered
  __shared__ int toks[LSEQ];                         // token ids (clamped)

  // ---- Resident B fragments, split into h-half (k<128) and e-half (k>=128).
  // MFMA #ks consumes B[k = ks*32 + lq*8 + j][n], j = 0..7.
  bf16x8 bfragH[4][4], bfragE[4][4];
  if (!tree) {
#pragma unroll
    for (int g = 0; g < 4; g++) {
      const int n = g * 128 + w * 16 + lr;
#pragma unroll
      for (int ks = 0; ks < 4; ks++) {
        const int k0 = ks * 32 + lq * 8;
        {
          float4 lo = *(const float4*)(Whh_f + n * 128 + k0);
          float4 hi = *(const float4*)(Whh_f + n * 128 + k0 + 4);
          bf16x8 fr;
          fr[0] = (short)f2b(lo.x); fr[1] = (short)f2b(lo.y);
          fr[2] = (short)f2b(lo.z); fr[3] = (short)f2b(lo.w);
          fr[4] = (short)f2b(hi.x); fr[5] = (short)f2b(hi.y);
          fr[6] = (short)f2b(hi.z); fr[7] = (short)f2b(hi.w);
          bfragH[g][ks] = fr;
        }
        {
          float4 lo = *(const float4*)(Wih_f + n * 128 + k0);
          float4 hi = *(const float4*)(Wih_f + n * 128 + k0 + 4);
          bf16x8 fr;
          fr[0] = (short)f2b(lo.x); fr[1] = (short)f2b(lo.y);
          fr[2] = (short)f2b(lo.z); fr[3] = (short)f2b(lo.w);
          fr[4] = (short)f2b(hi.x); fr[5] = (short)f2b(hi.y);
          fr[6] = (short)f2b(hi.z); fr[7] = (short)f2b(hi.w);
          bfragE[g][ks] = fr;
        }
      }
    }
  } else {
#pragma unroll
    for (int g = 0; g < 4; g++) {
      const int col = (g < 3) ? (g * 128 + w * 16 + lr) : (w * 16 + lr);
#pragma unroll
      for (int ks = 0; ks < 4; ks++) {
        const int k0 = ks * 32 + lq * 8;
        bf16x8 fh, fe;
#pragma unroll
        for (int j = 0; j < 8; j++) {
          const int k = k0 + j;
          float vh, ve;
          if (g < 3) { vh = Uiou[k * 384 + col]; ve = Wiou[k * 384 + col]; }
          else       { vh = Uf[k * 128 + col];   ve = Wf[k * 128 + col]; }
          fh[j] = (short)f2b(vh);
          fe[j] = (short)f2b(ve);
        }
        bfragH[g][ks] = fh;
        bfragE[g][ks] = fe;
      }
    }
  }

  // Per-lane biases for the 4 gates of d (all lanes; quadrants identical).
  // Consumed only inside EBATCH (baked into estage), not on the step path.
  float bias0, bias1, bias2, bias3;
  if (!tree) {
    bias0 = b_f[d];        bias1 = b_f[128 + d];
    bias2 = b_f[256 + d];  bias3 = b_f[384 + d];
  } else {
    bias0 = biou[d];       bias1 = biou[128 + d];
    bias2 = biou[256 + d]; bias3 = bfv[d];
  }

  // Token ids -> LDS (clamped); h(0) = 0 in both buffers.
  for (int i = tid; i < LSEQ; i += 512) {
    int tt = (i < len) ? i : (len - 1);
    toks[i] = x[tt * BN + b];
  }
  if (tid < HH) { aK[0][tid] = 0; aK[1][tid] = 0; }

  // Per-lane LDS byte bases (loop-invariant; per-step offsets are immediates).
  char* const es_base = (char*)estage;
  const int erd = (w << 12) + (lr << 4);               // estage read:  + S*256
  const int ewr = (w << 12) + (lq << 10) + (lr << 4);  // estage write: + rg*256
  const char* const ak_rd = (const char*)aK + (lq << 4);  // + (S&1)*256 + ks*64
  u16* const ak_wr = &aK[0][0] + d;                       // + ((S&1)^1)*128

  const f32x4 zf = (f32x4){0.f, 0.f, 0.f, 0.f};
  float c = 0.f, h = 0.f;
  int t = 0;

// ---- Batched e-half for steps [T0, T0+16): A row r = e(T0+r), r = lane&15.
// Output staged to wave-private estage WITH per-gate bias added (off the
// serial step path): lane q*16+lr holds step q*4+rg at reg rg.
#define EBATCH(T0)                                                            \
  {                                                                           \
    const int rb = ((T0) & (CHUNK - 1)) + lr;                                 \
    bf16x8 ae[4];                                                             \
    _Pragma("unroll")                                                         \
    for (int ks = 0; ks < 4; ks++) {                                          \
      int bo = (rb * 256 + ks * 64 + lq * 16) ^ ((rb & 7) << 4);              \
      ae[ks] = *(const bf16x8*)((const char*)echunk + bo);                    \
    }                                                                         \
    f32x4 EBv[4];                                                             \
    _Pragma("unroll")                                                         \
    for (int g = 0; g < 4; g++)                                               \
      EBv[g] = __builtin_amdgcn_mfma_f32_16x16x32_bf16(ae[0], bfragE[g][0],   \
                                                       zf, 0, 0, 0);          \
    _Pragma("unroll")                                                         \
    for (int ks = 1; ks < 4; ks++)                                            \
      _Pragma("unroll")                                                       \
      for (int g = 0; g < 4; g++)                                             \
        EBv[g] = __builtin_amdgcn_mfma_f32_16x16x32_bf16(                     \
            ae[ks], bfragE[g][ks], EBv[g], 0, 0, 0);                          \
    _Pragma("unroll")                                                         \
    for (int rg = 0; rg < 4; rg++) {                                          \
      f32x4 wv = {EBv[0][rg] + bias0, EBv[1][rg] + bias1,                     \
                  EBv[2][rg] + bias2, EBv[3][rg] + bias3};                    \
      *(f32x4*)(es_base + ewr + rg * 256) = wv;                               \
    }                                                                         \
  }

// ---- One step, compile-time step index S in [0,16). aK parity, estage
// offset fold to immediates. MFMA dependency depth = 2 (pair-split).
#define STEPB(S)                                                              \
  {                                                                           \
    bf16x8 ah[4];                                                             \
    _Pragma("unroll")                                                         \
    for (int ks = 0; ks < 4; ks++)                                            \
      ah[ks] = *(const bf16x8*)(ak_rd + ((S) & 1) * 256 + ks * 64);           \
    f32x4 ev = *(const f32x4*)(es_base + erd + (S) * 256);                    \
    f32x4 accA[4], accB[4];                                                   \
    _Pragma("unroll")                                                         \
    for (int g = 0; g < 4; g++) {                                             \
      accA[g] = __builtin_amdgcn_mfma_f32_16x16x32_bf16(ah[0], bfragH[g][0],  \
                                                        zf, 0, 0, 0);         \
      accB[g] = __builtin_amdgcn_mfma_f32_16x16x32_bf16(ah[2], bfragH[g][2],  \
                                                        zf, 0, 0, 0);         \
    }                                                                         \
    _Pragma("unroll")                                                         \
    for (int g = 0; g < 4; g++) {                                             \
      accA[g] = __builtin_amdgcn_mfma_f32_16x16x32_bf16(                      \
          ah[1], bfragH[g][1], accA[g], 0, 0, 0);                             \
      accB[g] = __builtin_amdgcn_mfma_f32_16x16x32_bf16(                      \
          ah[3], bfragH[g][3], accB[g], 0, 0, 0);                             \
    }                                                                         \
    float g0 = accA[0][0] + accB[0][0] + ev[0];                               \
    float g1 = accA[1][0] + accB[1][0] + ev[1];                               \
    float g2 = accA[2][0] + accB[2][0] + ev[2];                               \
    float g3 = accA[3][0] + accB[3][0] + ev[3];                               \
    if (!tree) {                                                              \
      float ii = sigm(g0), ff = sigm(g1), gg = tanh_f(g2), oo = sigm(g3);     \
      c = ff * c + ii * gg;                                                   \
      h = oo * tanh_f(c);                                                     \
    } else {                                                                  \
      float ii = sigm(g0), oo = sigm(g1), uu = tanh_f(g2), fl = sigm(g3);     \
      c = ii * uu + fl * c;                                                   \
      h = oo * tanh_f(c);                                                     \
    }                                                                         \
    unsigned hp = cvt_pk_bf16(h, h);                                          \
    if (l < 16) ak_wr[(((S) & 1) ^ 1) * 128] = (u16)hp;                       \
    __syncthreads();                                                          \
  }

// Tail step: block-uniform predicate (tend identical across waves), so the
// embedded __syncthreads is uniformly executed or skipped.
#define STEPT(S) if (tb + (S) < tend) STEPB(S)

  for (int c0 = 0; c0 < len; c0 += CHUNK) {
    __syncthreads();  // prev chunk fully consumed (and toks/h0 visible)

    // ---- Refill: stage rows [c0, c0+CHUNK) as bf16 into echunk (swizzled).
#pragma unroll
    for (int j = 0; j < 4; j++) {
      int u = tid + j * 512;
      int r = u >> 5;
      int c4 = (u & 31) * 4;
      int row = toks[c0 + r];
      float4 v = *(const float4*)(embed + (size_t)row * DD + c4);
      unsigned p01 = cvt_pk_bf16(v.x, v.y);
      unsigned p23 = cvt_pk_bf16(v.z, v.w);
      unsigned long long packed =
          (unsigned long long)p01 | ((unsigned long long)p23 << 32);
      int bo = (r * 256 + c4 * 2) ^ ((r & 7) << 4);
      *(unsigned long long*)((char*)echunk + bo) = packed;
    }
    __syncthreads();  // chunk visible

    const int tend = (c0 + CHUNK < len) ? c0 + CHUNK : len;
    // Full 16-step groups: no per-step checks, all offsets immediate.
    while (t + 16 <= tend) {
      EBATCH(t)
      STEPB(0)  STEPB(1)  STEPB(2)  STEPB(3)
      STEPB(4)  STEPB(5)  STEPB(6)  STEPB(7)
      STEPB(8)  STEPB(9)  STEPB(10) STEPB(11)
      STEPB(12) STEPB(13) STEPB(14) STEPB(15)
      t += 16;
    }
    // Tail group (only at the very end of the sequence).
    if (t < tend) {
      const int tb = t;
      EBATCH(tb)
      STEPT(0)  STEPT(1)  STEPT(2)  STEPT(3)
      STEPT(4)  STEPT(5)  STEPT(6)  STEPT(7)
      STEPT(8)  STEPT(9)  STEPT(10) STEPT(11)
      STEPT(12) STEPT(13) STEPT(14)
      t = tend;
    }
  }
#undef STEPT
#undef STEPB
#undef EBATCH

  if (l < 16) {
    if (!tree) {
      sent_vec[b * HH + d] = h;
    } else {
      t_state[b * HH + d] = c;
      t_hidden[b * HH + d] = h;
    }
  }
}

// ---------------------------------------------------------------------------
// Head: tree_out = [t_state | w1*t_hidden + w2*sent_vec]; sigmoid logits ->
// clipped BCE vs one-hot(y); loss = -mean over (B, NC=2) = 128 terms. fp32.
// ---------------------------------------------------------------------------
__global__ __launch_bounds__(128) void final_kernel(
    const int* __restrict__ y, const float* __restrict__ sent_vec,
    const float* __restrict__ t_state, const float* __restrict__ t_hidden,
    const float* __restrict__ Wout, const float* __restrict__ bout,
    const float* __restrict__ w1, const float* __restrict__ w2,
    float* __restrict__ out) {
  int tid = threadIdx.x;  // (b, cls)
  int b = tid >> 1, cls = tid & 1;
  float W1 = w1[0], W2 = w2[0];
  const float* wrow = Wout + cls * 256;
  float acc = bout[cls];
  for (int j = 0; j < HH; j++)
    acc += t_state[b * HH + j] * wrow[j];
  for (int j = 0; j < HH; j++)
    acc += (W1 * t_hidden[b * HH + j] + W2 * sent_vec[b * HH + j]) * wrow[128 + j];
  float p = 1.f / (1.f + __expf(-acc));
  p = fminf(1.f - 1e-7f, fmaxf(1e-7f, p));
  int yy = y[b]; yy = yy < 0 ? 0 : (yy > 1 ? 1 : yy);
  float term = (cls == yy) ? __logf(p) : __logf(1.f - p);
  __shared__ float red[128];
  red[tid] = term;
  __syncthreads();
  for (int s = 64; s > 0; s >>= 1) {
    if (tid < s) red[tid] += red[tid + s];
    __syncthreads();
  }
  if (tid == 0) out[0] = -red[0] / 128.f;
}

// ---------------------------------------------------------------------------
extern "C" void kernel_launch(void* const* d_in, const int* in_sizes, int n_in,
                              void* d_out, int out_size, void* d_ws, size_t ws_size,
                              hipStream_t stream) {
  (void)in_sizes; (void)n_in; (void)out_size; (void)ws_size;
  const int*   x       = (const int*)d_in[0];
  const int*   y       = (const int*)d_in[1];
  // d_in[2] = p (unused by reference)
  const int*   lengths = (const int*)d_in[3];
  // d_in[4], d_in[5] = left/right child: fixed left-deep chain (j-1 / -1)
  const float* embed   = (const float*)d_in[6];
  const float* Wih_f   = (const float*)d_in[7];
  const float* Whh_f   = (const float*)d_in[8];
  const float* b_f     = (const float*)d_in[9];
  // d_in[10..12] = backward-LSTM weights (result unused by reference)
  const float* Wiou    = (const float*)d_in[13];
  const float* Uiou    = (const float*)d_in[14];
  const float* biou    = (const float*)d_in[15];
  const float* Wf      = (const float*)d_in[16];
  const float* Uf      = (const float*)d_in[17];
  const float* bfv     = (const float*)d_in[18];
  const float* Wout    = (const float*)d_in[19];
  const float* bout    = (const float*)d_in[20];
  const float* w1      = (const float*)d_in[21];
  const float* w2      = (const float*)d_in[22];

  // Workspace: 3 fp32 [64][128] vectors = 96 KiB.
  float* sent_vec = (float*)d_ws;
  float* t_state  = sent_vec + BN * HH;
  float* t_hidden = t_state + BN * HH;

  chains_kernel<<<128, 512, 0, stream>>>(x, lengths, embed,
                                         Wih_f, Whh_f, b_f,
                                         Wiou, Uiou, biou, Wf, Uf, bfv,
                                         sent_vec, t_state, t_hidden);
  final_kernel<<<1, 128, 0, stream>>>(y, sent_vec, t_state, t_hidden,
                                      Wout, bout, w1, w2, (float*)d_out);
}